// Round 9
// baseline (3313.111 us; speedup 1.0000x reference)
//
#include <hip/hip_runtime.h>
#include <math.h>

typedef unsigned short u16;
typedef __attribute__((ext_vector_type(8))) short bf16x8;   // MFMA A/B frag
typedef __attribute__((ext_vector_type(4))) float f32x4;    // MFMA C/D frag

#define T_STEPS 32
#define BSZ     32
#define N_IN    64
#define H       256
#define N_OUT   64
#define ESTRIDE 9984              // rows = 320*31 + 64
#define CLAMP_MIN (-2.0f)
#define CLAMP_MAX ( 2.0f)
#define NSLOT   16                // block-slots per sample

// Fragment-packed layout: chunk = (row>>4)*8 + (k>>5), 512 u16/chunk,
// within-chunk elem = (((k&31)>>3)*16 + (row&15))*8 + (k&7).

__device__ inline u16 f2bf(float x) {                       // RTNE fp32->bf16
    unsigned u = __builtin_bit_cast(unsigned, x);
    unsigned r = u + 0x7FFFu + ((u >> 16) & 1u);
    return (u16)(r >> 16);
}

// ---------------------------------------------------------------------------
__global__ void init_k(float* __restrict__ p) {             // zero radT + rad_o
    p[blockIdx.x * 256 + threadIdx.x] = 0.0f;
}

// ---------------------------------------------------------------------------
__global__ void transpose_k(const float* __restrict__ src, float* __restrict__ dst,
                            int R, int C)
{
    __shared__ float tile[32][33];
    int bi = blockIdx.y, bj = blockIdx.x;
    int r0 = threadIdx.x >> 5, c = threadIdx.x & 31;
    #pragma unroll
    for (int rr = 0; rr < 4; ++rr) {
        int r = r0 * 4 + rr;
        tile[r][c] = src[(bi * 32 + r) * C + bj * 32 + c];
    }
    __syncthreads();
    #pragma unroll
    for (int rr = 0; rr < 4; ++rr) {
        int r = r0 * 4 + rr;
        dst[(bj * 32 + r) * R + bi * 32 + c] = tile[c][r];
    }
}

// ---------------------------------------------------------------------------
// prep0: head_pre_0, fresh rows [0,64) frag-packed, rad[0]. grid BSZ x 256.
// ---------------------------------------------------------------------------
__global__ __launch_bounds__(256) void prep0_k(
    const float* __restrict__ X0, const float* __restrict__ eps,
    const float* __restrict__ Wih, const float* __restrict__ bih,
    const float* __restrict__ bhh,
    float* __restrict__ hp0, float* __restrict__ rad0, u16* __restrict__ err)
{
    __shared__ float hx[N_IN], rr[N_IN], rad_s[H];
    const int b = blockIdx.x, tid = threadIdx.x;
    if (tid < N_IN) {
        float x = X0[b * N_IN + tid], e = eps[b];
        float l = fmaxf(x - e, CLAMP_MIN), u = fminf(x + e, CLAMP_MAX);
        hx[tid] = 0.5f * (l + u);
        rr[tid] = 0.5f * (u - l);
    }
    rad_s[tid] = 0.f;
    __syncthreads();

    float acc = bih[tid] + bhh[tid];
    #pragma unroll 8
    for (int i = 0; i < N_IN; ++i) acc += hx[i] * Wih[i * H + tid];
    hp0[b * H + tid] = acc;

    u16* errB = err + (size_t)b * ESTRIDE * H;
    const int e = tid * 2, q = e >> 7, m = (e >> 3) & 15, j = e & 7;
    #pragma unroll
    for (int ti = 0; ti < 4; ++ti) {
        int i = ti * 16 + m;
        float rho = rr[i];
        #pragma unroll
        for (int kc = 0; kc < 8; ++kc) {
            int k = kc * 32 + q * 8 + j;
            float v0 = rho * Wih[(size_t)i * H + k];
            float v1 = rho * Wih[(size_t)i * H + k + 1];
            unsigned pk = (unsigned)f2bf(v0) | ((unsigned)f2bf(v1) << 16);
            *(unsigned*)&errB[(size_t)(ti * 8 + kc) * 512 + e] = pk;
            atomicAdd(&rad_s[k], fabsf(v0));
            atomicAdd(&rad_s[k + 1], fabsf(v1));
        }
    }
    __syncthreads();
    atomicAdd(&rad0[b * H + tid], rad_s[tid]);
}

// ---------------------------------------------------------------------------
// step_k (one per t>=1): fused tanh prologue (redundant per block) +
// register B-slab (lam folded, no WT materialization) + task list:
//   tau < ntiles   : in-place gemm tile (rows [tau*64,+64))    [r7 verified]
//   tau-ntiles<4   : diag quarter rows diag_lo + [(tau-nt)*64,+64)
//   tau-ntiles==4  : fresh rows [E_old, E_old+64)
//   tau-ntiles==5  : head GEMV -> hp_new
// No intra-dispatch cross-block read-after-write. grid (NSLOT, BSZ).
// ---------------------------------------------------------------------------
__global__ __launch_bounds__(256, 2) void step_k(
    const float* __restrict__ Xt, const float* __restrict__ eps,
    const float* __restrict__ Wih, const float* __restrict__ Whh,
    const float* __restrict__ WhhT32,
    const float* __restrict__ bih, const float* __restrict__ bhh,
    const float* __restrict__ hp_prev, float* __restrict__ hp_new,
    const float* __restrict__ rad_prev, float* __restrict__ rad_new,
    u16* __restrict__ err, int E_old)
{
    __shared__ u16 tbuf[4][4096];          // 32 KB transform buffer
    __shared__ float lam_s[H], de_s[H], hh_s[H], radacc[H];
    __shared__ float hxm[N_IN], hxr[N_IN];
    const int slot = blockIdx.x, b = blockIdx.y;
    const int tid = threadIdx.x, wave = tid >> 6, lane = tid & 63;
    const int m = lane & 15, q = lane >> 4;
    const int e = tid * 2, qe = e >> 7, me = (e >> 3) & 15, je = e & 7;
    const int diag_lo = E_old - H, ntiles = diag_lo >> 6;
    u16* errB = err + (size_t)b * ESTRIDE * H;

    {   // tanh prologue (redundant per block; inputs complete from prev dispatch)
        float hd = hp_prev[b * H + tid], r = rad_prev[b * H + tid];
        float l = hd - r, u2 = hd + r;
        float tl = tanhf(l), tu = tanhf(u2);
        float la = fminf(1.f - tl * tl, 1.f - tu * tu);
        float mu = 0.5f * (tu + tl - la * (u2 + l));
        float dd = 0.5f * (tu - tl - la * (u2 - l));
        lam_s[tid] = la; de_s[tid] = dd; hh_s[tid] = la * hd + mu;
        radacc[tid] = 0.f;
        if (tid < N_IN) {
            float x = Xt[b * N_IN + tid], ebs = eps[b];
            float lo = fmaxf(x - ebs, CLAMP_MIN), up = fminf(x + ebs, CLAMP_MAX);
            hxm[tid] = 0.5f * (lo + up);
            hxr[tid] = 0.5f * (up - lo);
        }
    }
    __syncthreads();

    // B-slab in registers: WT[n][k] = f2bf(lam[k]*WhhT32[n][k]),
    // n = (wave*4+nt)*16+m, k = kc*32+q*8+j  (matches r7 gemm frag addressing)
    bf16x8 bfr[4][8];
    #pragma unroll
    for (int nt = 0; nt < 4; ++nt) {
        const float* src = WhhT32 + (size_t)((wave * 4 + nt) * 16 + m) * H;
        #pragma unroll
        for (int kc = 0; kc < 8; ++kc) {
            int k0 = kc * 32 + q * 8;
            union { u16 us[8]; bf16x8 v; } pk;
            #pragma unroll
            for (int j2 = 0; j2 < 8; ++j2)
                pk.us[j2] = f2bf(lam_s[k0 + j2] * src[k0 + j2]);
            bfr[nt][kc] = pk.v;
        }
    }

    const int ntask = ntiles + 6;
    for (int tau = slot; tau < ntask; tau += NSLOT) {
        if (tau < ntiles) {
            // ---- in-place gemm tile (r7 verified path) ----
            const int tile = tau;
            f32x4 acc[4][4];
            #pragma unroll
            for (int i = 0; i < 4; ++i)
                #pragma unroll
                for (int c = 0; c < 4; ++c) acc[i][c] = (f32x4){0.f, 0.f, 0.f, 0.f};
            #pragma unroll
            for (int kc = 0; kc < 8; ++kc) {
                bf16x8 af[4];
                #pragma unroll
                for (int rt = 0; rt < 4; ++rt)
                    af[rt] = *(const bf16x8*)&errB[(size_t)((tile * 4 + rt) * 8 + kc) * 512 + lane * 8];
                #pragma unroll
                for (int nt = 0; nt < 4; ++nt)
                    #pragma unroll
                    for (int rt = 0; rt < 4; ++rt)
                        acc[rt][nt] = __builtin_amdgcn_mfma_f32_16x16x32_bf16(
                            af[rt], bfr[nt][kc], acc[rt][nt], 0, 0, 0);
            }
            __syncthreads();   // all waves consumed A before in-place stores
            u16* W_ = tbuf[wave];
            #pragma unroll
            for (int nt = 0; nt < 4; ++nt) {
                int c32 = (nt & 1) * 16 + m;
                int q_a = c32 >> 3, jj = c32 & 7, kcl = nt >> 1;
                float s = 0.f;
                #pragma unroll
                for (int rt = 0; rt < 4; ++rt)
                    #pragma unroll
                    for (int r = 0; r < 4; ++r) {
                        float v = acc[rt][nt][r];
                        s += fabsf(v);
                        W_[rt * 1024 + kcl * 512 + (q_a * 16 + q * 4 + r) * 8 + jj] = f2bf(v);
                    }
                atomicAdd(&radacc[wave * 64 + nt * 16 + m], s);
            }
            #pragma unroll
            for (int rt = 0; rt < 4; ++rt)
                #pragma unroll
                for (int kcl = 0; kcl < 2; ++kcl) {
                    uint4 v = *(uint4*)&W_[rt * 1024 + kcl * 512 + lane * 8];
                    *(uint4*)&errB[(size_t)((tile * 4 + rt) * 8 + wave * 2 + kcl) * 512 + lane * 8] = v;
                }
        } else {
            int r = tau - ntiles;
            if (r < 4) {
                // ---- diag quarter: rows diag_lo + [r*64, +64) ----
                #pragma unroll
                for (int ti = 0; ti < 4; ++ti) {
                    int rsrc = r * 64 + ti * 16 + me;
                    float dv = de_s[rsrc];
                    const float* wrow = Whh + (size_t)rsrc * H;
                    #pragma unroll
                    for (int kc = 0; kc < 8; ++kc) {
                        int k = kc * 32 + qe * 8 + je;
                        float v0 = dv * wrow[k], v1 = dv * wrow[k + 1];
                        unsigned pv = (unsigned)f2bf(v0) | ((unsigned)f2bf(v1) << 16);
                        *(unsigned*)&errB[(size_t)(((diag_lo >> 4) + r * 4 + ti) * 8 + kc) * 512 + e] = pv;
                        atomicAdd(&radacc[k], fabsf(v0));
                        atomicAdd(&radacc[k + 1], fabsf(v1));
                    }
                }
            } else if (r == 4) {
                // ---- fresh rows [E_old, E_old+64) ----
                #pragma unroll
                for (int ti = 0; ti < 4; ++ti) {
                    int i = ti * 16 + me;
                    float rho = hxr[i];
                    const float* wrow = Wih + (size_t)i * H;
                    #pragma unroll
                    for (int kc = 0; kc < 8; ++kc) {
                        int k = kc * 32 + qe * 8 + je;
                        float v0 = rho * wrow[k], v1 = rho * wrow[k + 1];
                        unsigned pv = (unsigned)f2bf(v0) | ((unsigned)f2bf(v1) << 16);
                        *(unsigned*)&errB[(size_t)(((E_old >> 4) + ti) * 8 + kc) * 512 + e] = pv;
                        atomicAdd(&radacc[k], fabsf(v0));
                        atomicAdd(&radacc[k + 1], fabsf(v1));
                    }
                }
            } else {
                // ---- head GEMV -> hp_new ----
                float acc2 = bih[tid] + bhh[tid];
                #pragma unroll 8
                for (int i = 0; i < N_IN; ++i) acc2 += hxm[i] * Wih[i * H + tid];
                #pragma unroll 8
                for (int j2 = 0; j2 < H; ++j2) acc2 += hh_s[j2] * Whh[j2 * H + tid];
                hp_new[b * H + tid] = acc2;
            }
        }
    }
    __syncthreads();
    atomicAdd(&rad_new[b * H + tid], radacc[tid]);
}

// ---------------------------------------------------------------------------
// final_k: fused tanh(last) + WoT frags (lam folded, registers) +
// 39 radius tiles + head GEMV (+ final diag radius). grid (NSLOT, BSZ).
// rad_o pre-zeroed by init_k.
// ---------------------------------------------------------------------------
__global__ __launch_bounds__(256, 2) void final_k(
    const float* __restrict__ hp_last, const float* __restrict__ rad_last,
    const float* __restrict__ WoT32, const float* __restrict__ Wo,
    const float* __restrict__ bo_v, const u16* __restrict__ err,
    float* __restrict__ head_o, float* __restrict__ rad_o)
{
    __shared__ float lam_s[H], de_s[H], hh_s[H], radacc[N_OUT];
    const int slot = blockIdx.x, b = blockIdx.y;
    const int tid = threadIdx.x, wave = tid >> 6, lane = tid & 63;
    const int m = lane & 15, q = lane >> 4;
    const u16* errB = err + (size_t)b * ESTRIDE * H;

    {
        float hd = hp_last[b * H + tid], r = rad_last[b * H + tid];
        float l = hd - r, u2 = hd + r;
        float tl = tanhf(l), tu = tanhf(u2);
        float la = fminf(1.f - tl * tl, 1.f - tu * tu);
        float mu = 0.5f * (tu + tl - la * (u2 + l));
        float dd = 0.5f * (tu - tl - la * (u2 - l));
        lam_s[tid] = la; de_s[tid] = dd; hh_s[tid] = la * hd + mu;
        if (tid < N_OUT) radacc[tid] = 0.f;
    }
    __syncthreads();

    // WoT frags: n = nt*16+m, k = kc*32+q*8+j (lam folded)
    bf16x8 bq[4][8];
    #pragma unroll
    for (int nt = 0; nt < 4; ++nt) {
        const float* src = WoT32 + (size_t)(nt * 16 + m) * H;
        #pragma unroll
        for (int kc = 0; kc < 8; ++kc) {
            int k0 = kc * 32 + q * 8;
            union { u16 us[8]; bf16x8 v; } pk;
            #pragma unroll
            for (int j2 = 0; j2 < 8; ++j2)
                pk.us[j2] = f2bf(lam_s[k0 + j2] * src[k0 + j2]);
            bq[nt][kc] = pk.v;
        }
    }

    const int NT_OUT = ESTRIDE / 256;                  // 39 tiles of 256 rows
    for (int tau = slot; tau < NT_OUT + 1; tau += NSLOT) {
        if (tau < NT_OUT) {
            const int tile0 = tau * 16 + wave * 4;
            f32x4 acc[4][4];
            #pragma unroll
            for (int i = 0; i < 4; ++i)
                #pragma unroll
                for (int c = 0; c < 4; ++c) acc[i][c] = (f32x4){0.f, 0.f, 0.f, 0.f};
            #pragma unroll
            for (int kc = 0; kc < 8; ++kc) {
                bf16x8 af[4];
                #pragma unroll
                for (int rt = 0; rt < 4; ++rt)
                    af[rt] = *(const bf16x8*)&errB[(size_t)((tile0 + rt) * 8 + kc) * 512 + lane * 8];
                #pragma unroll
                for (int nt = 0; nt < 4; ++nt)
                    #pragma unroll
                    for (int rt = 0; rt < 4; ++rt)
                        acc[rt][nt] = __builtin_amdgcn_mfma_f32_16x16x32_bf16(
                            af[rt], bq[nt][kc], acc[rt][nt], 0, 0, 0);
            }
            #pragma unroll
            for (int nt = 0; nt < 4; ++nt) {
                float s = 0.f;
                #pragma unroll
                for (int rt = 0; rt < 4; ++rt)
                    #pragma unroll
                    for (int r = 0; r < 4; ++r) s += fabsf(acc[rt][nt][r]);
                atomicAdd(&radacc[nt * 16 + m], s);
            }
        } else if (tid < N_OUT) {
            // head GEMV + final diag radius
            float acc2 = bo_v[tid], accR = 0.f;
            #pragma unroll 4
            for (int j2 = 0; j2 < H; ++j2) {
                float w = Wo[j2 * N_OUT + tid];
                acc2 += hh_s[j2] * w;
                accR += fabsf(de_s[j2] * w);
            }
            head_o[b * N_OUT + tid] = acc2;
            atomicAdd(&rad_o[b * N_OUT + tid], accR);
        }
    }
    __syncthreads();
    if (tid < N_OUT) atomicAdd(&rad_o[b * N_OUT + tid], radacc[tid]);
}

// ---------------------------------------------------------------------------
__global__ void combine_k(const float* __restrict__ head_o,
                          const float* __restrict__ rad_o,
                          float* __restrict__ out)
{
    int i = blockIdx.x * 256 + threadIdx.x;
    if (i < BSZ * N_OUT) {
        float h = head_o[i], r = rad_o[i];
        out[i]               = h - r;
        out[BSZ * N_OUT + i] = h + r;
    }
}

// ---------------------------------------------------------------------------
extern "C" void kernel_launch(void* const* d_in, const int* in_sizes, int n_in,
                              void* d_out, int out_size, void* d_ws, size_t ws_size,
                              hipStream_t stream)
{
    const float* X    = (const float*)d_in[0];
    const float* eps  = (const float*)d_in[1];
    const float* Wih  = (const float*)d_in[2];
    const float* Whh  = (const float*)d_in[3];
    const float* bih  = (const float*)d_in[4];
    const float* bhh  = (const float*)d_in[5];
    const float* Wo   = (const float*)d_in[6];
    const float* bo   = (const float*)d_in[7];
    float* out = (float*)d_out;

    char* p = (char*)d_ws;
    u16* errP      = (u16*)p;   p += (size_t)BSZ * ESTRIDE * H * 2;   // 163.6 MB
    float* WhhT32  = (float*)p; p += (size_t)H * H * 4;
    float* WoT32   = (float*)p; p += (size_t)N_OUT * H * 4;
    float* hp      = (float*)p; p += (size_t)2 * BSZ * H * 4;
    float* radT    = (float*)p; p += (size_t)T_STEPS * BSZ * H * 4;   // zeroed
    float* rad_o   = (float*)p; p += (size_t)BSZ * N_OUT * 4;         // zeroed (contig)
    float* head_o  = (float*)p;

    // zero radT + rad_o (contiguous)
    init_k<<<(T_STEPS * BSZ * H + BSZ * N_OUT) / 256, 256, 0, stream>>>(radT);
    transpose_k<<<dim3(H / 32, H / 32), 256, 0, stream>>>(Whh, WhhT32, H, H);
    transpose_k<<<dim3(N_OUT / 32, H / 32), 256, 0, stream>>>(Wo, WoT32, H, N_OUT);

    prep0_k<<<BSZ, 256, 0, stream>>>(X, eps, Wih, bih, bhh, hp, radT, errP);

    for (int t = 1; t < T_STEPS; ++t) {
        const float* hp_prev  = hp + (size_t)((t - 1) & 1) * BSZ * H;
        float*       hp_new   = hp + (size_t)(t & 1) * BSZ * H;
        const float* rad_prev = radT + (size_t)(t - 1) * BSZ * H;
        float*       rad_new  = radT + (size_t)t * BSZ * H;
        step_k<<<dim3(NSLOT, BSZ), 256, 0, stream>>>(
            X + (size_t)t * BSZ * N_IN, eps, Wih, Whh, WhhT32, bih, bhh,
            hp_prev, hp_new, rad_prev, rad_new, errP, t * (N_IN + H));
    }

    final_k<<<dim3(NSLOT, BSZ), 256, 0, stream>>>(
        hp + (size_t)((T_STEPS - 1) & 1) * BSZ * H,
        radT + (size_t)(T_STEPS - 1) * BSZ * H,
        WoT32, Wo, bo, errP, head_o, rad_o);

    combine_k<<<(BSZ * N_OUT + 255) / 256, 256, 0, stream>>>(head_o, rad_o, out);
}